// Round 1
// baseline (78.878 us; speedup 1.0000x reference)
//
#include <hip/hip_runtime.h>

#define NSPLIT  4
#define NLAYERS 4
#define QPS     4
#define DIM     16
#define NCLS    5
#define BLK     256

struct c32 { float x, y; };
__device__ __forceinline__ c32 cmul(c32 a, c32 b) { return c32{a.x*b.x - a.y*b.y, a.x*b.y + a.y*b.x}; }
__device__ __forceinline__ c32 cadd(c32 a, c32 b) { return c32{a.x + b.x, a.y + b.y}; }

// ---------------------------------------------------------------------------
// Kernel A: build the per-split 16x16 total unitary by applying the circuit to
// each basis column. 64 threads = 4 splits x 16 columns, each thread owns one
// column (16 complex amplitudes) in LDS.
// ---------------------------------------------------------------------------
__global__ void build_unitary_kernel(const float* __restrict__ w,
                                     float* __restrict__ Ur,
                                     float* __restrict__ Ui)
{
    __shared__ c32 st[64][DIM];
    const int t = threadIdx.x;            // 0..63
    const int s = t >> 4, col = t & 15;

    for (int d = 0; d < DIM; ++d) st[t][d] = c32{ (d == col) ? 1.0f : 0.0f, 0.0f };

    for (int l = 0; l < NLAYERS; ++l) {
        // single-qubit rotations: U = RZ * RY * RX on wire j (wire 0 = MSB)
        for (int j = 0; j < QPS; ++j) {
            const float* wp = w + (((s * NLAYERS) + l) * QPS + j) * 3;
            const float hx = 0.5f * wp[0], hy = 0.5f * wp[1], hz = 0.5f * wp[2];
            const float cx = cosf(hx), sx = sinf(hx);
            const float cy = cosf(hy), sy = sinf(hy);
            const float cz = cosf(hz), sz = sinf(hz);
            // RX = [[cx, -i sx],[-i sx, cx]]   (X10 == X01)
            const c32 X00{cx, 0.f}, X01{0.f, -sx}, X11{cx, 0.f};
            // RY = [[cy, -sy],[sy, cy]]
            const c32 Y00{cy, 0.f}, Y01{-sy, 0.f}, Y10{sy, 0.f}, Y11{cy, 0.f};
            // RZ = diag(e^{-i hz}, e^{+i hz})
            const c32 Z00{cz, -sz}, Z11{cz, sz};
            // M = RY * RX
            const c32 M00 = cadd(cmul(Y00, X00), cmul(Y01, X01));
            const c32 M01 = cadd(cmul(Y00, X01), cmul(Y01, X11));
            const c32 M10 = cadd(cmul(Y10, X00), cmul(Y11, X01));
            const c32 M11 = cadd(cmul(Y10, X01), cmul(Y11, X11));
            // U = RZ * M
            const c32 U00 = cmul(Z00, M00), U01 = cmul(Z00, M01);
            const c32 U10 = cmul(Z11, M10), U11 = cmul(Z11, M11);

            const int p = 1 << (3 - j);   // wire j lives at bit (3-j)
            for (int i0 = 0; i0 < DIM; ++i0) {
                if (i0 & p) continue;
                const int i1 = i0 | p;
                const c32 a = st[t][i0], b = st[t][i1];
                st[t][i0] = cadd(cmul(U00, a), cmul(U01, b));
                st[t][i1] = cadd(cmul(U10, a), cmul(U11, b));
            }
        }
        // CNOT ring: ctrl j -> tgt (j+1)%4
        for (int j = 0; j < QPS; ++j) {
            const int j2 = (j + 1) & 3;
            const int pc = 1 << (3 - j), pt = 1 << (3 - j2);
            for (int i = 0; i < DIM; ++i) {
                if ((i & pc) && !(i & pt)) {
                    const int i1 = i | pt;
                    const c32 a = st[t][i];
                    st[t][i]  = st[t][i1];
                    st[t][i1] = a;
                }
            }
        }
    }

    for (int d = 0; d < DIM; ++d) {
        Ur[(s * DIM + d) * DIM + col] = st[t][d].x;
        Ui[(s * DIM + d) * DIM + col] = st[t][d].y;
    }
}

// ---------------------------------------------------------------------------
// Kernel B: one thread per batch row. Quantum features via two real 16x16
// matvecs per split, then the 16->128->64->5 MLP, weights staged in LDS.
// ---------------------------------------------------------------------------
__global__ __launch_bounds__(BLK) void qcnn_main_kernel(
    const float* __restrict__ x,
    const float* __restrict__ Ur, const float* __restrict__ Ui,
    const float* __restrict__ W1, const float* __restrict__ b1,
    const float* __restrict__ W2, const float* __restrict__ b2,
    const float* __restrict__ W3, const float* __restrict__ b3,
    float* __restrict__ out, int B)
{
    __shared__ __align__(16) float sUr[NSPLIT * DIM * DIM];   // 4 KB
    __shared__ __align__(16) float sUi[NSPLIT * DIM * DIM];   // 4 KB
    __shared__ __align__(16) float sW1t[128 * 16];            // 8 KB, [k1][f]
    __shared__ float sb1[128];
    __shared__ __align__(16) float sW2[128 * 64];             // 32 KB, [k1][k2]
    __shared__ float sb2[64];
    __shared__ float sW3[64 * NCLS];
    __shared__ float sb3[NCLS];

    const int tid = threadIdx.x;
    for (int i = tid; i < NSPLIT * DIM * DIM; i += BLK) { sUr[i] = Ur[i]; sUi[i] = Ui[i]; }
    for (int i = tid; i < 128 * 16; i += BLK) {
        const int k1 = i >> 4, f = i & 15;
        sW1t[i] = W1[f * 128 + k1];                 // transpose so row k1 is contiguous
    }
    for (int i = tid; i < 128;      i += BLK) sb1[i] = b1[i];
    for (int i = tid; i < 128 * 64; i += BLK) sW2[i] = W2[i];
    for (int i = tid; i < 64;       i += BLK) sb2[i] = b2[i];
    for (int i = tid; i < 64 * NCLS; i += BLK) sW3[i] = W3[i];
    for (int i = tid; i < NCLS;     i += BLK) sb3[i] = b3[i];
    __syncthreads();

    const int b = blockIdx.x * BLK + tid;
    if (b >= B) return;

    // ---- quantum features ----
    float feats[16];
    const float4* xp = (const float4*)(x + (size_t)b * (NSPLIT * DIM));
    #pragma unroll
    for (int s = 0; s < NSPLIT; ++s) {
        float v[16];
        {
            const float4 v0 = xp[s * 4 + 0], v1 = xp[s * 4 + 1];
            const float4 v2 = xp[s * 4 + 2], v3 = xp[s * 4 + 3];
            v[0]=v0.x;  v[1]=v0.y;  v[2]=v0.z;  v[3]=v0.w;
            v[4]=v1.x;  v[5]=v1.y;  v[6]=v1.z;  v[7]=v1.w;
            v[8]=v2.x;  v[9]=v2.y;  v[10]=v2.z; v[11]=v2.w;
            v[12]=v3.x; v[13]=v3.y; v[14]=v3.z; v[15]=v3.w;
        }
        float nrm2 = 0.f;
        #pragma unroll
        for (int c = 0; c < 16; ++c) nrm2 += v[c] * v[c];
        const float inv = (nrm2 > 0.f) ? rsqrtf(nrm2) : 1.0f;
        #pragma unroll
        for (int c = 0; c < 16; ++c) v[c] *= inv;

        float e0 = 0.f, e1 = 0.f, e2 = 0.f, e3 = 0.f;
        #pragma unroll
        for (int d = 0; d < DIM; ++d) {
            const float4* ur = (const float4*)(sUr + (s * DIM + d) * DIM);
            const float4* ui = (const float4*)(sUi + (s * DIM + d) * DIM);
            float yr = 0.f, yi = 0.f;
            #pragma unroll
            for (int cq = 0; cq < 4; ++cq) {
                const float4 u = ur[cq], wv = ui[cq];
                yr += u.x  * v[4*cq] + u.y  * v[4*cq+1] + u.z  * v[4*cq+2] + u.w  * v[4*cq+3];
                yi += wv.x * v[4*cq] + wv.y * v[4*cq+1] + wv.z * v[4*cq+2] + wv.w * v[4*cq+3];
            }
            const float p = yr * yr + yi * yi;
            e0 += (d & 8) ? -p : p;   // wire 0 = MSB
            e1 += (d & 4) ? -p : p;
            e2 += (d & 2) ? -p : p;
            e3 += (d & 1) ? -p : p;
        }
        feats[s * 4 + 0] = e0;
        feats[s * 4 + 1] = e1;
        feats[s * 4 + 2] = e2;
        feats[s * 4 + 3] = e3;
    }

    // ---- MLP: 16 -> 128 (relu) -> 64 (relu) -> 5 ----
    float h2[64];
    #pragma unroll
    for (int k2 = 0; k2 < 64; ++k2) h2[k2] = sb2[k2];

    for (int k1 = 0; k1 < 128; ++k1) {
        const float4* w1r = (const float4*)(sW1t + k1 * 16);
        float a = sb1[k1];
        #pragma unroll
        for (int fq = 0; fq < 4; ++fq) {
            const float4 wv = w1r[fq];
            a += wv.x * feats[4*fq] + wv.y * feats[4*fq+1] + wv.z * feats[4*fq+2] + wv.w * feats[4*fq+3];
        }
        a = fmaxf(a, 0.f);   // relu
        const float4* w2r = (const float4*)(sW2 + k1 * 64);
        #pragma unroll
        for (int q = 0; q < 16; ++q) {
            const float4 wv = w2r[q];
            h2[4*q+0] += a * wv.x;
            h2[4*q+1] += a * wv.y;
            h2[4*q+2] += a * wv.z;
            h2[4*q+3] += a * wv.w;
        }
    }
    #pragma unroll
    for (int k2 = 0; k2 < 64; ++k2) h2[k2] = fmaxf(h2[k2], 0.f);

    float o[NCLS];
    #pragma unroll
    for (int j = 0; j < NCLS; ++j) o[j] = sb3[j];
    #pragma unroll
    for (int k2 = 0; k2 < 64; ++k2) {
        const float h = h2[k2];
        #pragma unroll
        for (int j = 0; j < NCLS; ++j) o[j] += h * sW3[k2 * NCLS + j];
    }
    #pragma unroll
    for (int j = 0; j < NCLS; ++j) out[(size_t)b * NCLS + j] = o[j];
}

extern "C" void kernel_launch(void* const* d_in, const int* in_sizes, int n_in,
                              void* d_out, int out_size, void* d_ws, size_t ws_size,
                              hipStream_t stream)
{
    const float* x  = (const float*)d_in[0];
    const float* sw = (const float*)d_in[1];
    const float* W1 = (const float*)d_in[2];
    const float* b1 = (const float*)d_in[3];
    const float* W2 = (const float*)d_in[4];
    const float* b2 = (const float*)d_in[5];
    const float* W3 = (const float*)d_in[6];
    const float* b3 = (const float*)d_in[7];
    float* out = (float*)d_out;

    float* Ur = (float*)d_ws;
    float* Ui = Ur + NSPLIT * DIM * DIM;

    const int B = in_sizes[0] / (NSPLIT * DIM);

    hipLaunchKernelGGL(build_unitary_kernel, dim3(1), dim3(64), 0, stream, sw, Ur, Ui);

    const int grid = (B + BLK - 1) / BLK;
    hipLaunchKernelGGL(qcnn_main_kernel, dim3(grid), dim3(BLK), 0, stream,
                       x, Ur, Ui, W1, b1, W2, b2, W3, b3, out, B);
}

// Round 2
// 55.815 us; speedup vs baseline: 1.4132x; 1.4132x over previous
//
#include <hip/hip_runtime.h>

#define NSPLIT  4
#define NLAYERS 4
#define QPS     4
#define DIM     16
#define NCLS    5
#define BLK     256
#define RROWS   32

// LDS layout strides (words)
#define U_SS      520          // per-split stride: 16 rows * 32 words + 8 pad -> s*8 bank offset
#define FE_STRIDE 17
#define H1_STRIDE 33
#define H2_STRIDE 68

struct c32 { float x, y; };
__device__ __forceinline__ c32 cmul(c32 a, c32 b) { return c32{a.x*b.x - a.y*b.y, a.x*b.y + a.y*b.x}; }
__device__ __forceinline__ c32 cadd(c32 a, c32 b) { return c32{a.x + b.x, a.y + b.y}; }

// ---------------------------------------------------------------------------
// Kernel A: per-split 16x16 total unitary, one basis column per thread,
// statevector kept entirely in registers (all indices compile-time).
// ---------------------------------------------------------------------------
__global__ void build_unitary_kernel(const float* __restrict__ w,
                                     float* __restrict__ Ur,
                                     float* __restrict__ Ui)
{
    const int t = threadIdx.x;            // 0..63
    const int s = t >> 4, col = t & 15;

    float str[DIM], sti[DIM];
    #pragma unroll
    for (int d = 0; d < DIM; ++d) { str[d] = (d == col) ? 1.0f : 0.0f; sti[d] = 0.0f; }

    #pragma unroll
    for (int l = 0; l < NLAYERS; ++l) {
        #pragma unroll
        for (int j = 0; j < QPS; ++j) {
            const float* wp = w + (((s * NLAYERS) + l) * QPS + j) * 3;
            const float hx = 0.5f * wp[0], hy = 0.5f * wp[1], hz = 0.5f * wp[2];
            float sx, cx, sy, cy, sz, cz;
            sincosf(hx, &sx, &cx);
            sincosf(hy, &sy, &cy);
            sincosf(hz, &sz, &cz);
            const c32 X00{cx, 0.f}, X01{0.f, -sx}, X11{cx, 0.f};
            const c32 Y00{cy, 0.f}, Y01{-sy, 0.f}, Y10{sy, 0.f}, Y11{cy, 0.f};
            const c32 Z00{cz, -sz}, Z11{cz, sz};
            const c32 M00 = cadd(cmul(Y00, X00), cmul(Y01, X01));
            const c32 M01 = cadd(cmul(Y00, X01), cmul(Y01, X11));
            const c32 M10 = cadd(cmul(Y10, X00), cmul(Y11, X01));
            const c32 M11 = cadd(cmul(Y10, X01), cmul(Y11, X11));
            const c32 U00 = cmul(Z00, M00), U01 = cmul(Z00, M01);
            const c32 U10 = cmul(Z11, M10), U11 = cmul(Z11, M11);

            const int p = 8 >> j;         // wire j at bit (3-j)
            #pragma unroll
            for (int i0 = 0; i0 < DIM; ++i0) {
                if (i0 & p) continue;
                const int i1 = i0 | p;
                const float ar = str[i0], ai = sti[i0];
                const float br = str[i1], bi = sti[i1];
                str[i0] = U00.x*ar - U00.y*ai + U01.x*br - U01.y*bi;
                sti[i0] = U00.x*ai + U00.y*ar + U01.x*bi + U01.y*br;
                str[i1] = U10.x*ar - U10.y*ai + U11.x*br - U11.y*bi;
                sti[i1] = U10.x*ai + U10.y*ar + U11.x*bi + U11.y*br;
            }
        }
        // CNOT ring
        #pragma unroll
        for (int j = 0; j < QPS; ++j) {
            const int pc = 8 >> j, pt = 8 >> ((j + 1) & 3);
            #pragma unroll
            for (int i = 0; i < DIM; ++i) {
                if ((i & pc) && !(i & pt)) {
                    const int i1 = i | pt;
                    float tr = str[i]; str[i] = str[i1]; str[i1] = tr;
                    float ti = sti[i]; sti[i] = sti[i1]; sti[i1] = ti;
                }
            }
        }
    }

    #pragma unroll
    for (int d = 0; d < DIM; ++d) {
        Ur[(s * DIM + d) * DIM + col] = str[d];
        Ui[(s * DIM + d) * DIM + col] = sti[d];
    }
}

// ---------------------------------------------------------------------------
// Kernel B: cooperative 32-row tiles, 256 threads/block, 1024 blocks.
// Phases: stage -> quantum feats -> W1 -> W2 -> W3, intermediates in LDS.
// ---------------------------------------------------------------------------
__global__ __launch_bounds__(BLK) void qcnn_main_kernel(
    const float* __restrict__ x,
    const float* __restrict__ Ug,          // Ur[1024] then Ui[1024]
    const float* __restrict__ W1, const float* __restrict__ b1,
    const float* __restrict__ W2, const float* __restrict__ b2,
    const float* __restrict__ W3, const float* __restrict__ b3,
    float* __restrict__ out, int B)
{
    __shared__ __align__(16) float sU[NSPLIT * U_SS];            // 8320 B (re/im interleaved, padded)
    __shared__ __align__(16) float sW1[128 * 16];                // 8192 B  [k1][f]
    __shared__ __align__(16) float sW2[128 * 64];                // 32768 B [k1][k2]
    __shared__ __align__(16) float sFe[RROWS * FE_STRIDE];       // 2176 B
    __shared__ __align__(16) float sH1[128 * H1_STRIDE];         // 16896 B [k1][r]
    __shared__ __align__(16) float sH2[RROWS * H2_STRIDE];       // 8704 B  [r][k2]
    __shared__ float sb1[128], sb2[64], sW3b[64 * NCLS], sb3[NCLS];

    const int t = threadIdx.x;
    const int row0 = blockIdx.x * RROWS;

    // ---- stage weights ----
    {
        const float* Urg = Ug;
        const float* Uig = Ug + 1024;
        for (int i = t; i < 1024; i += BLK) {
            const int s = i >> 8, d = (i >> 4) & 15, c = i & 15;
            const int wd = s * U_SS + d * 32 + 2 * c;
            sU[wd] = Urg[i]; sU[wd + 1] = Uig[i];
        }
        for (int i = t; i < 2048; i += BLK) {
            const int k1 = i >> 4, f = i & 15;
            sW1[i] = W1[f * 128 + k1];                 // transpose: row k1 contiguous
        }
        for (int i = t; i < 2048; i += BLK)
            ((float4*)sW2)[i] = ((const float4*)W2)[i];
        if (t < 128) sb1[t] = b1[t];
        if (t < 64)  sb2[t] = b2[t];
        for (int i = t; i < 64 * NCLS; i += BLK) sW3b[i] = W3[i];
        if (t < NCLS) sb3[t] = b3[t];
    }
    __syncthreads();

    // ---- phase Q: quantum features. thread = (row, split, d-half) ----
    {
        const int u = t >> 1, dh = t & 1;
        const int r = u >> 2, s = u & 3;
        int row = row0 + r; if (row >= B) row = B - 1;   // clamp (writes guarded later)

        float v[16];
        const float4* xp = (const float4*)(x + (size_t)row * 64 + s * 16);
        const float4 a0 = xp[0], a1 = xp[1], a2 = xp[2], a3 = xp[3];
        v[0]=a0.x;  v[1]=a0.y;  v[2]=a0.z;  v[3]=a0.w;
        v[4]=a1.x;  v[5]=a1.y;  v[6]=a1.z;  v[7]=a1.w;
        v[8]=a2.x;  v[9]=a2.y;  v[10]=a2.z; v[11]=a2.w;
        v[12]=a3.x; v[13]=a3.y; v[14]=a3.z; v[15]=a3.w;

        float n2 = 0.f;
        #pragma unroll
        for (int c = 0; c < 16; ++c) n2 += v[c] * v[c];
        const float inv2 = (n2 > 0.f) ? (1.0f / n2) : 1.0f;   // probs scale by 1/||v||^2

        float e0 = 0.f, e1 = 0.f, e2 = 0.f, e3 = 0.f;
        const float* ub = sU + s * U_SS + dh * (8 * 32);
        #pragma unroll
        for (int i = 0; i < 8; ++i) {
            const int d = dh * 8 + i;
            const float4* up = (const float4*)(ub + i * 32);
            float yr = 0.f, yi = 0.f;
            #pragma unroll
            for (int cp = 0; cp < 8; ++cp) {
                const float4 uu = up[cp];       // (re_c, im_c, re_{c+1}, im_{c+1})
                yr += uu.x * v[2*cp] + uu.z * v[2*cp + 1];
                yi += uu.y * v[2*cp] + uu.w * v[2*cp + 1];
            }
            const float p = (yr * yr + yi * yi) * inv2;
            e0 += (d & 8) ? -p : p;
            e1 += (d & 4) ? -p : p;
            e2 += (d & 2) ? -p : p;
            e3 += (d & 1) ? -p : p;
        }
        e0 += __shfl_xor(e0, 1);
        e1 += __shfl_xor(e1, 1);
        e2 += __shfl_xor(e2, 1);
        e3 += __shfl_xor(e3, 1);
        if (dh == 0) {
            float* fp = sFe + r * FE_STRIDE + s * 4;
            fp[0] = e0; fp[1] = e1; fp[2] = e2; fp[3] = e3;
        }
    }
    __syncthreads();

    // ---- phase M1: h1 = relu(feats @ W1 + b1), store transposed [k1][r] ----
    {
        const int r = t & 31, k1g = t >> 5;      // 8 groups of 16 k1
        float fv[16];
        #pragma unroll
        for (int f = 0; f < 16; ++f) fv[f] = sFe[r * FE_STRIDE + f];
        #pragma unroll
        for (int kk = 0; kk < 16; ++kk) {
            const int k1 = k1g * 16 + kk;
            const float4* wp = (const float4*)(sW1 + k1 * 16);
            const float4 w0 = wp[0], w1 = wp[1], w2 = wp[2], w3 = wp[3];
            float a = sb1[k1]
                + w0.x*fv[0]  + w0.y*fv[1]  + w0.z*fv[2]  + w0.w*fv[3]
                + w1.x*fv[4]  + w1.y*fv[5]  + w1.z*fv[6]  + w1.w*fv[7]
                + w2.x*fv[8]  + w2.y*fv[9]  + w2.z*fv[10] + w2.w*fv[11]
                + w3.x*fv[12] + w3.y*fv[13] + w3.z*fv[14] + w3.w*fv[15];
            sH1[k1 * H1_STRIDE + r] = fmaxf(a, 0.f);
        }
    }
    __syncthreads();

    // ---- phase M2: h2 = relu(h1 @ W2 + b2). thread = (row, 8 k2's) ----
    {
        const int oct = t & 7, r = t >> 3;       // r 0..31
        float acc[8];
        #pragma unroll
        for (int j = 0; j < 8; ++j) acc[j] = sb2[oct * 8 + j];
        const float*  h1p = sH1 + r;
        const float4* w2p = ((const float4*)sW2) + oct * 2;
        #pragma unroll 4
        for (int k1 = 0; k1 < 128; ++k1) {
            const float h = h1p[k1 * H1_STRIDE];           // broadcast (8 lanes/addr)
            const float4 wa = w2p[k1 * 16];
            const float4 wb = w2p[k1 * 16 + 1];
            acc[0] += h * wa.x; acc[1] += h * wa.y; acc[2] += h * wa.z; acc[3] += h * wa.w;
            acc[4] += h * wb.x; acc[5] += h * wb.y; acc[6] += h * wb.z; acc[7] += h * wb.w;
        }
        float4 o0, o1;
        o0.x = fmaxf(acc[0], 0.f); o0.y = fmaxf(acc[1], 0.f);
        o0.z = fmaxf(acc[2], 0.f); o0.w = fmaxf(acc[3], 0.f);
        o1.x = fmaxf(acc[4], 0.f); o1.y = fmaxf(acc[5], 0.f);
        o1.z = fmaxf(acc[6], 0.f); o1.w = fmaxf(acc[7], 0.f);
        float4* hp = (float4*)(sH2 + r * H2_STRIDE + oct * 8);
        hp[0] = o0; hp[1] = o1;
    }
    __syncthreads();

    // ---- phase M3: out = h2 @ W3 + b3. thread = (row, class), 160 active ----
    if (t < RROWS * NCLS) {
        const int r = t / NCLS, j = t - r * NCLS;
        float acc = sb3[j];
        const float4* hp = (const float4*)(sH2 + r * H2_STRIDE);
        #pragma unroll
        for (int q = 0; q < 16; ++q) {
            const float4 h = hp[q];
            acc += h.x * sW3b[(4*q + 0) * NCLS + j]
                 + h.y * sW3b[(4*q + 1) * NCLS + j]
                 + h.z * sW3b[(4*q + 2) * NCLS + j]
                 + h.w * sW3b[(4*q + 3) * NCLS + j];
        }
        const int row = row0 + r;
        if (row < B) out[(size_t)row * NCLS + j] = acc;
    }
}

extern "C" void kernel_launch(void* const* d_in, const int* in_sizes, int n_in,
                              void* d_out, int out_size, void* d_ws, size_t ws_size,
                              hipStream_t stream)
{
    (void)n_in; (void)out_size; (void)ws_size;
    const float* x  = (const float*)d_in[0];
    const float* sw = (const float*)d_in[1];
    const float* W1 = (const float*)d_in[2];
    const float* b1 = (const float*)d_in[3];
    const float* W2 = (const float*)d_in[4];
    const float* b2 = (const float*)d_in[5];
    const float* W3 = (const float*)d_in[6];
    const float* b3 = (const float*)d_in[7];
    float* out = (float*)d_out;

    float* Ur = (float*)d_ws;                  // 1024 floats
    float* Ui = Ur + 1024;                     // 1024 floats

    const int B = in_sizes[0] / (NSPLIT * DIM);

    hipLaunchKernelGGL(build_unitary_kernel, dim3(1), dim3(64), 0, stream, sw, Ur, Ui);

    const int grid = (B + RROWS - 1) / RROWS;
    hipLaunchKernelGGL(qcnn_main_kernel, dim3(grid), dim3(BLK), 0, stream,
                       x, (const float*)d_ws, W1, b1, W2, b2, W3, b3, out, B);
}

// Round 3
// 39.402 us; speedup vs baseline: 2.0019x; 1.4165x over previous
//
#include <hip/hip_runtime.h>

#define NSPLIT  4
#define NLAYERS 4
#define QPS     4
#define DIM     16
#define NCLS    5
#define BLK     256
#define RROWS   32

// LDS layout strides (words)
#define U_SS      520          // per-split stride: 16 rows * 32 words + 8 pad -> s*8 bank offset
#define FE_STRIDE 17
#define H1_STRIDE 33
#define H2_STRIDE 68

struct c32 { float x, y; };
__device__ __forceinline__ c32 cmul(c32 a, c32 b) { return c32{a.x*b.x - a.y*b.y, a.x*b.y + a.y*b.x}; }
__device__ __forceinline__ c32 cadd(c32 a, c32 b) { return c32{a.x + b.x, a.y + b.y}; }

// ---------------------------------------------------------------------------
// Kernel A: per-split 16x16 total unitary.
// Phase 1: 64 threads = (split, gate) each build one 2x2 gate (parallel
//          hardware sincos) -> LDS.
// Phase 2: 64 threads = (split, basis column) chain the 16 gates through a
//          register statevector (compile-time butterflies + CNOT perms).
// ---------------------------------------------------------------------------
__global__ void build_unitary_kernel(const float* __restrict__ w,
                                     float* __restrict__ Ur,
                                     float* __restrict__ Ui)
{
    __shared__ float gU[NSPLIT][NLAYERS * QPS][8];   // 2 KB

    const int t = threadIdx.x;            // 0..63

    // ---- phase 1: one gate per thread ----
    {
        const int s = t >> 4, g = t & 15;           // g = l*QPS + j
        const float* wp = w + (s * (NLAYERS * QPS) + g) * 3;
        const float hx = 0.5f * wp[0], hy = 0.5f * wp[1], hz = 0.5f * wp[2];
        float sx, cx, sy, cy, sz, cz;
        __sincosf(hx, &sx, &cx);
        __sincosf(hy, &sy, &cy);
        __sincosf(hz, &sz, &cz);
        const c32 X00{cx, 0.f}, X01{0.f, -sx}, X11{cx, 0.f};
        const c32 Y00{cy, 0.f}, Y01{-sy, 0.f}, Y10{sy, 0.f}, Y11{cy, 0.f};
        const c32 Z00{cz, -sz}, Z11{cz, sz};
        const c32 M00 = cadd(cmul(Y00, X00), cmul(Y01, X01));
        const c32 M01 = cadd(cmul(Y00, X01), cmul(Y01, X11));
        const c32 M10 = cadd(cmul(Y10, X00), cmul(Y11, X01));
        const c32 M11 = cadd(cmul(Y10, X01), cmul(Y11, X11));
        const c32 U00 = cmul(Z00, M00), U01 = cmul(Z00, M01);
        const c32 U10 = cmul(Z11, M10), U11 = cmul(Z11, M11);
        float* gp = gU[s][g];
        gp[0] = U00.x; gp[1] = U00.y; gp[2] = U01.x; gp[3] = U01.y;
        gp[4] = U10.x; gp[5] = U10.y; gp[6] = U11.x; gp[7] = U11.y;
    }
    __syncthreads();

    // ---- phase 2: chain gates through a register statevector ----
    const int s = t >> 4, col = t & 15;
    float str[DIM], sti[DIM];
    #pragma unroll
    for (int d = 0; d < DIM; ++d) { str[d] = (d == col) ? 1.0f : 0.0f; sti[d] = 0.0f; }

    #pragma unroll
    for (int l = 0; l < NLAYERS; ++l) {
        #pragma unroll
        for (int j = 0; j < QPS; ++j) {
            const float* gp = gU[s][l * QPS + j];
            const float4 u0 = *(const float4*)gp;        // U00.x U00.y U01.x U01.y
            const float4 u1 = *(const float4*)(gp + 4);  // U10.x U10.y U11.x U11.y
            const int p = 8 >> j;                        // wire j at bit (3-j)
            #pragma unroll
            for (int i0 = 0; i0 < DIM; ++i0) {
                if (i0 & p) continue;
                const int i1 = i0 | p;
                const float ar = str[i0], ai = sti[i0];
                const float br = str[i1], bi = sti[i1];
                str[i0] = u0.x*ar - u0.y*ai + u0.z*br - u0.w*bi;
                sti[i0] = u0.x*ai + u0.y*ar + u0.z*bi + u0.w*br;
                str[i1] = u1.x*ar - u1.y*ai + u1.z*br - u1.w*bi;
                sti[i1] = u1.x*ai + u1.y*ar + u1.z*bi + u1.w*br;
            }
        }
        // CNOT ring (pure register permutation, resolved at compile time)
        #pragma unroll
        for (int j = 0; j < QPS; ++j) {
            const int pc = 8 >> j, pt = 8 >> ((j + 1) & 3);
            #pragma unroll
            for (int i = 0; i < DIM; ++i) {
                if ((i & pc) && !(i & pt)) {
                    const int i1 = i | pt;
                    float tr = str[i]; str[i] = str[i1]; str[i1] = tr;
                    float ti = sti[i]; sti[i] = sti[i1]; sti[i1] = ti;
                }
            }
        }
    }

    #pragma unroll
    for (int d = 0; d < DIM; ++d) {
        Ur[(s * DIM + d) * DIM + col] = str[d];
        Ui[(s * DIM + d) * DIM + col] = sti[d];
    }
}

// ---------------------------------------------------------------------------
// Kernel B: cooperative 32-row tiles, 256 threads/block, 1024 blocks.
// Phases: stage -> quantum feats -> W1 -> W2 -> W3, intermediates in LDS.
// ---------------------------------------------------------------------------
__global__ __launch_bounds__(BLK) void qcnn_main_kernel(
    const float* __restrict__ x,
    const float* __restrict__ Ug,          // Ur[1024] then Ui[1024]
    const float* __restrict__ W1, const float* __restrict__ b1,
    const float* __restrict__ W2, const float* __restrict__ b2,
    const float* __restrict__ W3, const float* __restrict__ b3,
    float* __restrict__ out, int B)
{
    __shared__ __align__(16) float sU[NSPLIT * U_SS];            // 8320 B (re/im interleaved, padded)
    __shared__ __align__(16) float sW1[128 * 16];                // 8192 B  [k1][f]
    __shared__ __align__(16) float sW2[128 * 64];                // 32768 B [k1][k2]
    __shared__ __align__(16) float sFe[RROWS * FE_STRIDE];       // 2176 B
    __shared__ __align__(16) float sH1[128 * H1_STRIDE];         // 16896 B [k1][r]
    __shared__ __align__(16) float sH2[RROWS * H2_STRIDE];       // 8704 B  [r][k2]
    __shared__ float sb1[128], sb2[64], sW3b[64 * NCLS], sb3[NCLS];

    const int t = threadIdx.x;
    const int row0 = blockIdx.x * RROWS;

    // ---- stage weights ----
    {
        const float* Urg = Ug;
        const float* Uig = Ug + 1024;
        for (int i = t; i < 1024; i += BLK) {
            const int s = i >> 8, d = (i >> 4) & 15, c = i & 15;
            const int wd = s * U_SS + d * 32 + 2 * c;
            sU[wd] = Urg[i]; sU[wd + 1] = Uig[i];
        }
        for (int i = t; i < 2048; i += BLK) {
            const int k1 = i >> 4, f = i & 15;
            sW1[i] = W1[f * 128 + k1];                 // transpose: row k1 contiguous
        }
        for (int i = t; i < 2048; i += BLK)
            ((float4*)sW2)[i] = ((const float4*)W2)[i];
        if (t < 128) sb1[t] = b1[t];
        if (t < 64)  sb2[t] = b2[t];
        for (int i = t; i < 64 * NCLS; i += BLK) sW3b[i] = W3[i];
        if (t < NCLS) sb3[t] = b3[t];
    }
    __syncthreads();

    // ---- phase Q: quantum features. thread = (row, split, d-half) ----
    {
        const int u = t >> 1, dh = t & 1;
        const int r = u >> 2, s = u & 3;
        int row = row0 + r; if (row >= B) row = B - 1;   // clamp (writes guarded later)

        float v[16];
        const float4* xp = (const float4*)(x + (size_t)row * 64 + s * 16);
        const float4 a0 = xp[0], a1 = xp[1], a2 = xp[2], a3 = xp[3];
        v[0]=a0.x;  v[1]=a0.y;  v[2]=a0.z;  v[3]=a0.w;
        v[4]=a1.x;  v[5]=a1.y;  v[6]=a1.z;  v[7]=a1.w;
        v[8]=a2.x;  v[9]=a2.y;  v[10]=a2.z; v[11]=a2.w;
        v[12]=a3.x; v[13]=a3.y; v[14]=a3.z; v[15]=a3.w;

        float n2 = 0.f;
        #pragma unroll
        for (int c = 0; c < 16; ++c) n2 += v[c] * v[c];
        const float inv2 = (n2 > 0.f) ? (1.0f / n2) : 1.0f;   // probs scale by 1/||v||^2

        float e0 = 0.f, e1 = 0.f, e2 = 0.f, e3 = 0.f;
        const float* ub = sU + s * U_SS + dh * (8 * 32);
        #pragma unroll
        for (int i = 0; i < 8; ++i) {
            const int d = dh * 8 + i;
            const float4* up = (const float4*)(ub + i * 32);
            float yr = 0.f, yi = 0.f;
            #pragma unroll
            for (int cp = 0; cp < 8; ++cp) {
                const float4 uu = up[cp];       // (re_c, im_c, re_{c+1}, im_{c+1})
                yr += uu.x * v[2*cp] + uu.z * v[2*cp + 1];
                yi += uu.y * v[2*cp] + uu.w * v[2*cp + 1];
            }
            const float p = (yr * yr + yi * yi) * inv2;
            e0 += (d & 8) ? -p : p;
            e1 += (d & 4) ? -p : p;
            e2 += (d & 2) ? -p : p;
            e3 += (d & 1) ? -p : p;
        }
        e0 += __shfl_xor(e0, 1);
        e1 += __shfl_xor(e1, 1);
        e2 += __shfl_xor(e2, 1);
        e3 += __shfl_xor(e3, 1);
        if (dh == 0) {
            float* fp = sFe + r * FE_STRIDE + s * 4;
            fp[0] = e0; fp[1] = e1; fp[2] = e2; fp[3] = e3;
        }
    }
    __syncthreads();

    // ---- phase M1: h1 = relu(feats @ W1 + b1), store transposed [k1][r] ----
    {
        const int r = t & 31, k1g = t >> 5;      // 8 groups of 16 k1
        float fv[16];
        #pragma unroll
        for (int f = 0; f < 16; ++f) fv[f] = sFe[r * FE_STRIDE + f];
        #pragma unroll
        for (int kk = 0; kk < 16; ++kk) {
            const int k1 = k1g * 16 + kk;
            const float4* wp = (const float4*)(sW1 + k1 * 16);
            const float4 w0 = wp[0], w1 = wp[1], w2 = wp[2], w3 = wp[3];
            float a = sb1[k1]
                + w0.x*fv[0]  + w0.y*fv[1]  + w0.z*fv[2]  + w0.w*fv[3]
                + w1.x*fv[4]  + w1.y*fv[5]  + w1.z*fv[6]  + w1.w*fv[7]
                + w2.x*fv[8]  + w2.y*fv[9]  + w2.z*fv[10] + w2.w*fv[11]
                + w3.x*fv[12] + w3.y*fv[13] + w3.z*fv[14] + w3.w*fv[15];
            sH1[k1 * H1_STRIDE + r] = fmaxf(a, 0.f);
        }
    }
    __syncthreads();

    // ---- phase M2: h2 = relu(h1 @ W2 + b2). thread = (row, 8 k2's) ----
    {
        const int oct = t & 7, r = t >> 3;       // r 0..31
        float acc[8];
        #pragma unroll
        for (int j = 0; j < 8; ++j) acc[j] = sb2[oct * 8 + j];
        const float*  h1p = sH1 + r;
        const float4* w2p = ((const float4*)sW2) + oct * 2;
        #pragma unroll 4
        for (int k1 = 0; k1 < 128; ++k1) {
            const float h = h1p[k1 * H1_STRIDE];           // broadcast (8 lanes/addr)
            const float4 wa = w2p[k1 * 16];
            const float4 wb = w2p[k1 * 16 + 1];
            acc[0] += h * wa.x; acc[1] += h * wa.y; acc[2] += h * wa.z; acc[3] += h * wa.w;
            acc[4] += h * wb.x; acc[5] += h * wb.y; acc[6] += h * wb.z; acc[7] += h * wb.w;
        }
        float4 o0, o1;
        o0.x = fmaxf(acc[0], 0.f); o0.y = fmaxf(acc[1], 0.f);
        o0.z = fmaxf(acc[2], 0.f); o0.w = fmaxf(acc[3], 0.f);
        o1.x = fmaxf(acc[4], 0.f); o1.y = fmaxf(acc[5], 0.f);
        o1.z = fmaxf(acc[6], 0.f); o1.w = fmaxf(acc[7], 0.f);
        float4* hp = (float4*)(sH2 + r * H2_STRIDE + oct * 8);
        hp[0] = o0; hp[1] = o1;
    }
    __syncthreads();

    // ---- phase M3: out = h2 @ W3 + b3. thread = (row, class), 160 active ----
    if (t < RROWS * NCLS) {
        const int r = t / NCLS, j = t - r * NCLS;
        float acc = sb3[j];
        const float4* hp = (const float4*)(sH2 + r * H2_STRIDE);
        #pragma unroll
        for (int q = 0; q < 16; ++q) {
            const float4 h = hp[q];
            acc += h.x * sW3b[(4*q + 0) * NCLS + j]
                 + h.y * sW3b[(4*q + 1) * NCLS + j]
                 + h.z * sW3b[(4*q + 2) * NCLS + j]
                 + h.w * sW3b[(4*q + 3) * NCLS + j];
        }
        const int row = row0 + r;
        if (row < B) out[(size_t)row * NCLS + j] = acc;
    }
}

extern "C" void kernel_launch(void* const* d_in, const int* in_sizes, int n_in,
                              void* d_out, int out_size, void* d_ws, size_t ws_size,
                              hipStream_t stream)
{
    (void)n_in; (void)out_size; (void)ws_size;
    const float* x  = (const float*)d_in[0];
    const float* sw = (const float*)d_in[1];
    const float* W1 = (const float*)d_in[2];
    const float* b1 = (const float*)d_in[3];
    const float* W2 = (const float*)d_in[4];
    const float* b2 = (const float*)d_in[5];
    const float* W3 = (const float*)d_in[6];
    const float* b3 = (const float*)d_in[7];
    float* out = (float*)d_out;

    float* Ur = (float*)d_ws;                  // 1024 floats
    float* Ui = Ur + 1024;                     // 1024 floats

    const int B = in_sizes[0] / (NSPLIT * DIM);

    hipLaunchKernelGGL(build_unitary_kernel, dim3(1), dim3(64), 0, stream, sw, Ur, Ui);

    const int grid = (B + RROWS - 1) / RROWS;
    hipLaunchKernelGGL(qcnn_main_kernel, dim3(grid), dim3(BLK), 0, stream,
                       x, (const float*)d_ws, W1, b1, W2, b2, W3, b3, out, B);
}